// Round 10
// baseline (2283.756 us; speedup 1.0000x reference)
//
#include <hip/hip_runtime.h>
#include <hip/hip_cooperative_groups.h>

namespace cg = cooperative_groups;

#define NDIM 128

typedef __attribute__((ext_vector_type(8))) short s16x8;
typedef __attribute__((ext_vector_type(8))) _Float16 h16x8;
typedef __attribute__((ext_vector_type(4))) float f32x4;

// fp32 <-> fp16 (RNE via hardware cvt)
__device__ __forceinline__ unsigned short f2h(float f) {
    _Float16 h = (_Float16)f;
    return *(unsigned short*)&h;
}
__device__ __forceinline__ float h2f(unsigned short u) {
    _Float16 h = *(_Float16*)&u;
    return (float)h;
}

// async global->LDS, 16 B per lane; lds dest is wave-uniform base
// (lane l lands at base + l*16). Source is per-lane (pre-swizzle there).
__device__ __forceinline__ void g2lds16(const void* g, void* l) {
    __builtin_amdgcn_global_load_lds(
        (const __attribute__((address_space(1))) void*)g,
        (__attribute__((address_space(3))) void*)l, 16, 0, 0);
}

// =====================================================================
// Cooperative mega-kernel (R10): the whole pipeline in ONE dispatch.
// 19 dispatches (~95 us of launch gaps) -> 1 dispatch + 16 grid syncs.
// Every phase body is the proven R9 code, loop-bounded (no early returns
// so every thread reaches every grid.sync). __threadfence() before each
// sync for cross-XCD L2 visibility (G16).
// =====================================================================
struct MegaArgs {
    const int* eraw;
    const float* Wl; const float* Wr; const float* bl; const float* x0;
    int* idx; int* deg; int* flag;
    int* row_start; int* cursor; int* partials; int* ssrc;
    float* invd;
    short* wfrag;
    short* f0; short* f1; short* f2;
    float* out;
    int N; int E;
};

#define GRID_FENCE_SYNC() do { __threadfence(); grid.sync(); } while (0)

__global__ __launch_bounds__(256, 4) void mega_kernel(MegaArgs a) {
    cg::grid_group grid = cg::this_grid();
    __shared__ __align__(16) short sT[2][64][64];   // 16 KB gemm staging
    __shared__ int sInt[256];                        // scan/reduce overlay
    const int tid = threadIdx.x;
    const int gtid = blockIdx.x * 256 + tid;
    const int gsz = gridDim.x * 256;
    const int N = a.N, E = a.E;
    const int nb = (N + 1023) >> 10;

    // ---- P0: zero deg[0..N] (deg+N is the layout flag) ----
    for (int i = gtid; i <= N; i += gsz) a.deg[i] = 0;
    GRID_FENCE_SYNC();

    // ---- P1: detect layout + presplit W + split x0 (independent) ----
    {
        const int samples = (E < 4096) ? E : 4096;
        for (int i = gtid; i < samples; i += gsz)
            if (a.eraw[2 * i + 1]) atomicOr(a.flag, 1);
        // presplit v3: W -> B-frag order, fp16 hi + lo*2^11 [m89/m91]
        for (int t = gtid; t < 327680; t += gsz) {
            int j = t & 7;
            int lane_ = (t >> 3) & 63;
            int ct = (t >> 9) & 7;
            int chunk = (t >> 12) & 3;
            int plane = (t >> 14) & 3;
            int l = t >> 16;
            int nn = ct * 16 + (lane_ & 15);
            int k = chunk * 32 + (lane_ >> 4) * 8 + j;
            const float* src = (plane < 2) ? a.Wl : a.Wr;
            float v = src[(size_t)l * 16384 + (size_t)k * 128 + nn];
            unsigned short h = f2h(v);
            a.wfrag[t] = (plane & 1) ? (short)f2h((v - h2f(h)) * 2048.0f) : (short)h;
        }
        const int total4 = N * 32;
        for (int i = gtid; i < total4; i += gsz) {
            float4 v = *(const float4*)(a.x0 + (size_t)i * 4);
            unsigned short f[4] = {f2h(v.x), f2h(v.y), f2h(v.z), f2h(v.w)};
            *(int2*)(a.f0 + (size_t)i * 4) = make_int2(
                (int)(f[0] | ((unsigned)f[1] << 16)), (int)(f[2] | ((unsigned)f[3] << 16)));
        }
    }
    GRID_FENCE_SYNC();

    // ---- P2: convert + fused degree histogram ----
    {
        const int fl = *a.flag;
        for (int i = gtid; i < 2 * E; i += gsz) {
            int v = (fl == 0) ? a.eraw[2 * i] : a.eraw[i];
            a.idx[i] = v;
            if (i >= E) atomicAdd(&a.deg[v], 1);
        }
    }
    GRID_FENCE_SYNC();

    // ---- P3: per-1024-chunk degree sums ----
    for (int c = blockIdx.x; c < nb; c += gridDim.x) {
        const int base = c << 10;
        int s = 0;
#pragma unroll
        for (int j = 0; j < 4; ++j) {
            int i = base + tid * 4 + j;
            if (i < N) s += a.deg[i];
        }
#pragma unroll
        for (int off = 32; off; off >>= 1) s += __shfl_down(s, off);
        if ((tid & 63) == 0) sInt[tid >> 6] = s;
        __syncthreads();
        if (tid == 0) a.partials[c] = sInt[0] + sInt[1] + sInt[2] + sInt[3];
        __syncthreads();
    }
    GRID_FENCE_SYNC();

    // ---- P4: scan partials (block 0; nb<=256 holds for N<=262144) ----
    if (blockIdx.x == 0) {
        int v = (tid < nb) ? a.partials[tid] : 0;
        sInt[tid] = v;
        __syncthreads();
        for (int off = 1; off < 256; off <<= 1) {
            int x = sInt[tid];
            int y = (tid >= off) ? sInt[tid - off] : 0;
            __syncthreads();
            sInt[tid] = x + y;
            __syncthreads();
        }
        if (tid < nb) a.partials[tid] = (tid == 0) ? 0 : sInt[tid - 1];
        if (tid == 0) a.row_start[N] = sInt[255];
    }
    GRID_FENCE_SYNC();

    // ---- P5: downsweep (row_start, cursor, inv_deg) ----
    for (int c = blockIdx.x; c < nb; c += gridDim.x) {
        const int base = c << 10;
        const int i0 = base + tid * 4;
        int d[4];
        int s = 0;
#pragma unroll
        for (int j = 0; j < 4; ++j) {
            int i = i0 + j;
            d[j] = (i < N) ? a.deg[i] : 0;
            s += d[j];
        }
        const int lane_ = tid & 63;
        int incl = s;
#pragma unroll
        for (int off = 1; off < 64; off <<= 1) {
            int t2 = __shfl_up(incl, off);
            if (lane_ >= off) incl += t2;
        }
        if (lane_ == 63) sInt[tid >> 6] = incl;
        __syncthreads();
        int woff = 0;
        const int w = tid >> 6;
        for (int k = 0; k < w; ++k) woff += sInt[k];
        int excl = incl - s + woff + a.partials[c];
#pragma unroll
        for (int j = 0; j < 4; ++j) {
            int i = i0 + j;
            if (i < N) {
                a.row_start[i] = excl;
                a.cursor[i] = excl;
                a.invd[i] = 1.0f / (float)max(d[j], 1);
                excl += d[j];
            }
        }
        __syncthreads();
    }
    GRID_FENCE_SYNC();

    // ---- P6: scatter (4 edges/thread ILP) ----
    for (int i0 = gtid * 4; i0 < E; i0 += gsz * 4) {
        int s[4], d[4], p[4];
#pragma unroll
        for (int j = 0; j < 4; ++j)
            if (i0 + j < E) { s[j] = a.idx[i0 + j]; d[j] = a.idx[E + i0 + j]; }
#pragma unroll
        for (int j = 0; j < 4; ++j)
            if (i0 + j < E) p[j] = atomicAdd(&a.cursor[d[j]], 1);
#pragma unroll
        for (int j = 0; j < 4; ++j)
            if (i0 + j < E) a.ssrc[p[j]] = s[j];
    }
    GRID_FENCE_SYNC();

    // ---- layers: 5 x (aggregate ; gemm) ----
    short* act[3] = {a.f0, a.f1, a.f2};
    int xs = 0;
    const int nbands = (N + 63) >> 6;
    const int lane = tid & 63;
    const int wave = tid >> 6;
    const int ln15 = lane & 15;
    const int quad = lane >> 4;
    const int wr0 = (wave & 1) * 32;
    const int wc0 = (wave >> 1) * 64;
    const int ctbase = (wave >> 1) * 4;
    const int rhalf = (wave & 1) * 32;
    const int rl8 = lane >> 3;
    const int gslot = (lane & 7) ^ rl8;
    const int lane32 = tid & 31;
    const int q4 = lane32 << 2;

    for (int l = 0; l < 5; ++l) {
        const short* X = act[xs];
        short* AG = act[(xs + 1) % 3];

        // aggregate v7 (fp16 in/out), grid-stride over nodes
        for (int node = gtid >> 5; node < N; node += gsz >> 5) {
            const int beg = a.row_start[node];
            const int end = a.row_start[node + 1];
            float4 acc = make_float4(0.f, 0.f, 0.f, 0.f);
            for (int base = beg; base < end; base += 32) {
                const int cnt = min(end - base, 32);
                const int my_src = (lane32 < cnt) ? a.ssrc[base + lane32] : 0;
                for (int jb = 0; jb < cnt; jb += 8) {
                    int2 v[8];
                    float m[8];
#pragma unroll
                    for (int t = 0; t < 8; ++t) {
                        const int j = jb + t;
                        const int js = (j < cnt) ? j : (cnt - 1);
                        const int s = __shfl(my_src, js, 32);
                        v[t] = *(const int2*)(X + (size_t)s * 128 + q4);
                        m[t] = (j < cnt) ? 1.f : 0.f;
                    }
#pragma unroll
                    for (int t = 0; t < 8; ++t) {
                        union { int2 i2; _Float16 h[4]; } u;
                        u.i2 = v[t];
                        acc.x = fmaf(m[t], (float)u.h[0], acc.x);
                        acc.y = fmaf(m[t], (float)u.h[1], acc.y);
                        acc.z = fmaf(m[t], (float)u.h[2], acc.z);
                        acc.w = fmaf(m[t], (float)u.h[3], acc.w);
                    }
                }
            }
            const float inv = a.invd[node];
            acc.x *= inv; acc.y *= inv; acc.z *= inv; acc.w *= inv;
            unsigned short f[4] = {f2h(acc.x), f2h(acc.y), f2h(acc.z), f2h(acc.w)};
            *(int2*)(AG + (size_t)node * 128 + q4) = make_int2(
                (int)(f[0] | ((unsigned)f[1] << 16)), (int)(f[2] | ((unsigned)f[3] << 16)));
        }
        GRID_FENCE_SYNC();

        // gemm v14 (fp16 MFMA, split-fp16 W), grid-stride over 64-row bands
        {
            float* Yf = (l == 4) ? a.out : nullptr;
            short* Y16 = (l < 4) ? act[(xs + 2) % 3] : nullptr;
            const short* wfl = a.wfrag + (size_t)l * 65536;
            const float* bias = a.bl + (size_t)l * 128;
            const short* pbase = (wave < 2) ? (const short*)AG : X;
            for (int band = blockIdx.x; band < nbands; band += gridDim.x) {
                const int row0 = band * 64;
                f32x4 accM[2][4], accR[2][4];
#pragma unroll
                for (int i = 0; i < 2; ++i)
#pragma unroll
                    for (int j = 0; j < 4; ++j) { accM[i][j] = (f32x4)(0.f); accR[i][j] = (f32x4)(0.f); }

                for (int kp = 0; kp < 2; ++kp) {
                    __syncthreads();   // prior reads done before overwrite
#pragma unroll
                    for (int i = 0; i < 4; ++i) {
                        const int rloc = rhalf + i * 8;
                        int grow = row0 + rloc + rl8;
                        if (grow >= N) grow = N - 1;
                        const short* g = pbase + (size_t)grow * 128 + kp * 64 + gslot * 8;
                        g2lds16(g, &sT[wave >> 1][rloc][0]);
                    }
                    __syncthreads();   // drains vmcnt(0)

#pragma unroll
                    for (int ch = 0; ch < 2; ++ch) {
                        const int chunk = kp * 2 + ch;
                        h16x8 fAg[2], fX[2];
#pragma unroll
                        for (int rt = 0; rt < 2; ++rt) {
                            const int r = wr0 + rt * 16 + ln15;
                            const int cc = (ch * 4 + quad) ^ (r & 7);
                            fAg[rt] = *(const h16x8*)&sT[0][r][cc * 8];
                            fX[rt]  = *(const h16x8*)&sT[1][r][cc * 8];
                        }
#pragma unroll
                        for (int ct = 0; ct < 4; ++ct) {
                            const short* wb = wfl + (chunk << 12) + ((ctbase + ct) << 9) + (lane << 3);
                            const h16x8 wlh = *(const h16x8*)(wb);
                            const h16x8 wll = *(const h16x8*)(wb + 16384);
                            const h16x8 wrh = *(const h16x8*)(wb + 32768);
                            const h16x8 wrl = *(const h16x8*)(wb + 49152);
#pragma unroll
                            for (int rt = 0; rt < 2; ++rt) {
                                accM[rt][ct] = __builtin_amdgcn_mfma_f32_16x16x32_f16(fAg[rt], wlh, accM[rt][ct], 0, 0, 0);
                                accR[rt][ct] = __builtin_amdgcn_mfma_f32_16x16x32_f16(fAg[rt], wll, accR[rt][ct], 0, 0, 0);
                                accM[rt][ct] = __builtin_amdgcn_mfma_f32_16x16x32_f16(fX[rt],  wrh, accM[rt][ct], 0, 0, 0);
                                accR[rt][ct] = __builtin_amdgcn_mfma_f32_16x16x32_f16(fX[rt],  wrl, accR[rt][ct], 0, 0, 0);
                            }
                        }
                    }
                }

                // epilogue: C/D col=lane&15, row=quad*4+reg [m89]
#pragma unroll
                for (int rt = 0; rt < 2; ++rt) {
#pragma unroll
                    for (int ct = 0; ct < 4; ++ct) {
                        const int col = wc0 + ct * 16 + ln15;
                        const float bv = bias[col];
#pragma unroll
                        for (int r = 0; r < 4; ++r) {
                            const int grow = row0 + wr0 + rt * 16 + quad * 4 + r;
                            if (grow < N) {
                                float v = accM[rt][ct][r] + accR[rt][ct][r] * 4.8828125e-4f + bv;
                                if (l < 4) v = fmaxf(v, 0.f);
                                if (Yf) {
                                    Yf[(size_t)grow * NDIM + col] = v;
                                } else {
                                    Y16[(size_t)grow * 128 + col] = (short)f2h(v);
                                }
                            }
                        }
                    }
                }
            }
        }
        if (l < 4) GRID_FENCE_SYNC();
        xs = (xs + 2) % 3;
    }
}

// =====================================================================
// Fallback path: the proven R9 separate-kernel pipeline (357.5 us).
// Used only if the cooperative launch is unavailable.
// =====================================================================
__global__ __launch_bounds__(256) void detect_kernel(
    const int* __restrict__ raw, int* __restrict__ flag, int E) {
    __shared__ int any_nz;
    if (threadIdx.x == 0) any_nz = 0;
    __syncthreads();
    int local = 0;
    const int samples = (E < 4096) ? E : 4096;
#pragma unroll
    for (int j = 0; j < 16; ++j) {
        int i = threadIdx.x * 16 + j;
        if (i < samples) local |= raw[2 * i + 1];
    }
    if (local) atomicOr(&any_nz, 1);
    __syncthreads();
    if (threadIdx.x == 0) *flag = any_nz;
}

__global__ void convert_kernel(const int* __restrict__ raw, const int* __restrict__ flag,
                               int* __restrict__ idx, int* __restrict__ deg, int E) {
    int i = blockIdx.x * 256 + threadIdx.x;
    if (i >= 2 * E) return;
    int v = (*flag == 0) ? raw[2 * i] : raw[i];
    idx[i] = v;
    if (i >= E) atomicAdd(&deg[v], 1);
}

__global__ __launch_bounds__(256) void deg_reduce_kernel(
    const int* __restrict__ deg, int* __restrict__ partials, int n) {
    const int base = blockIdx.x * 1024;
    const int tid = threadIdx.x;
    int s = 0;
#pragma unroll
    for (int j = 0; j < 4; ++j) {
        int i = base + tid * 4 + j;
        if (i < n) s += deg[i];
    }
#pragma unroll
    for (int off = 32; off; off >>= 1) s += __shfl_down(s, off);
    __shared__ int ws[4];
    if ((tid & 63) == 0) ws[tid >> 6] = s;
    __syncthreads();
    if (tid == 0) partials[blockIdx.x] = ws[0] + ws[1] + ws[2] + ws[3];
}

__global__ void scan_partials_kernel(int* __restrict__ partials, int nb,
                                     int* __restrict__ row_start, int n) {
    __shared__ int sh[1024];
    const int tid = threadIdx.x;
    int v = (tid < nb) ? partials[tid] : 0;
    sh[tid] = v;
    __syncthreads();
    for (int off = 1; off < 1024; off <<= 1) {
        int a = sh[tid];
        int b = (tid >= off) ? sh[tid - off] : 0;
        __syncthreads();
        sh[tid] = a + b;
        __syncthreads();
    }
    if (tid < nb) partials[tid] = (tid == 0) ? 0 : sh[tid - 1];
    if (tid == 0) row_start[n] = sh[1023];
}

__global__ __launch_bounds__(256) void deg_downsweep_kernel(
    const int* __restrict__ deg, const int* __restrict__ partials,
    int* __restrict__ row_start, int* __restrict__ cursor,
    float* __restrict__ inv_deg, int n) {
    const int base = blockIdx.x * 1024;
    const int tid = threadIdx.x;
    const int i0 = base + tid * 4;
    int d[4];
    int s = 0;
#pragma unroll
    for (int j = 0; j < 4; ++j) {
        int i = i0 + j;
        d[j] = (i < n) ? deg[i] : 0;
        s += d[j];
    }
    const int lane = tid & 63;
    int incl = s;
#pragma unroll
    for (int off = 1; off < 64; off <<= 1) {
        int t = __shfl_up(incl, off);
        if (lane >= off) incl += t;
    }
    __shared__ int wsum[4];
    if (lane == 63) wsum[tid >> 6] = incl;
    __syncthreads();
    int woff = 0;
    const int w = tid >> 6;
    for (int k = 0; k < w; ++k) woff += wsum[k];
    int excl = incl - s + woff + partials[blockIdx.x];
#pragma unroll
    for (int j = 0; j < 4; ++j) {
        int i = i0 + j;
        if (i < n) {
            row_start[i] = excl;
            cursor[i] = excl;
            inv_deg[i] = 1.0f / (float)max(d[j], 1);
            excl += d[j];
        }
    }
}

__global__ __launch_bounds__(256) void scatter_kernel(
    const int* __restrict__ idx, int* __restrict__ cursor,
    int* __restrict__ sorted_src, int E) {
    const int i0 = (blockIdx.x * 256 + threadIdx.x) * 4;
    if (i0 >= E) return;
    int s[4], d[4], p[4];
#pragma unroll
    for (int j = 0; j < 4; ++j) {
        if (i0 + j < E) {
            s[j] = idx[i0 + j];
            d[j] = idx[E + i0 + j];
        }
    }
#pragma unroll
    for (int j = 0; j < 4; ++j)
        if (i0 + j < E) p[j] = atomicAdd(&cursor[d[j]], 1);
#pragma unroll
    for (int j = 0; j < 4; ++j)
        if (i0 + j < E) sorted_src[p[j]] = s[j];
}

__global__ __launch_bounds__(256) void presplit_kernel(
    const float* __restrict__ Wl, const float* __restrict__ Wr,
    short* __restrict__ wfrag, int total) {
    int idx = blockIdx.x * 256 + threadIdx.x;
    if (idx >= total) return;
    int j = idx & 7;
    int lane = (idx >> 3) & 63;
    int ct = (idx >> 9) & 7;
    int chunk = (idx >> 12) & 3;
    int plane = (idx >> 14) & 3;
    int l = idx >> 16;
    int nn = ct * 16 + (lane & 15);
    int k = chunk * 32 + (lane >> 4) * 8 + j;
    const float* src = (plane < 2) ? Wl : Wr;
    float v = src[(size_t)l * 16384 + (size_t)k * 128 + nn];
    unsigned short h = f2h(v);
    wfrag[idx] = (plane & 1) ? (short)f2h((v - h2f(h)) * 2048.0f) : (short)h;
}

__global__ __launch_bounds__(256) void split_x_kernel(
    const float* __restrict__ X, short* __restrict__ Xf16, int total4) {
    int i = blockIdx.x * 256 + threadIdx.x;
    if (i >= total4) return;
    float4 v = *(const float4*)(X + (size_t)i * 4);
    unsigned short f[4] = {f2h(v.x), f2h(v.y), f2h(v.z), f2h(v.w)};
    *(int2*)(Xf16 + (size_t)i * 4) = make_int2(
        (int)(f[0] | ((unsigned)f[1] << 16)), (int)(f[2] | ((unsigned)f[3] << 16)));
}

__global__ __launch_bounds__(256) void aggregate_kernel(
    const short* __restrict__ Xf16, const int* __restrict__ row_start,
    const int* __restrict__ sorted_src, const float* __restrict__ inv_deg,
    short* __restrict__ Agf16, int n) {
    int gid = blockIdx.x * 256 + threadIdx.x;
    int node = gid >> 5;
    if (node >= n) return;
    const int lane32 = threadIdx.x & 31;
    const int q = lane32 << 2;
    const int beg = row_start[node];
    const int end = row_start[node + 1];
    float4 acc = make_float4(0.f, 0.f, 0.f, 0.f);
    for (int base = beg; base < end; base += 32) {
        const int cnt = min(end - base, 32);
        const int my_src = (lane32 < cnt) ? sorted_src[base + lane32] : 0;
        for (int jb = 0; jb < cnt; jb += 8) {
            int2 v[8];
            float m[8];
#pragma unroll
            for (int t = 0; t < 8; ++t) {
                const int j = jb + t;
                const int js = (j < cnt) ? j : (cnt - 1);
                const int s = __shfl(my_src, js, 32);
                v[t] = *(const int2*)(Xf16 + (size_t)s * 128 + q);
                m[t] = (j < cnt) ? 1.f : 0.f;
            }
#pragma unroll
            for (int t = 0; t < 8; ++t) {
                union { int2 i2; _Float16 h[4]; } u;
                u.i2 = v[t];
                acc.x = fmaf(m[t], (float)u.h[0], acc.x);
                acc.y = fmaf(m[t], (float)u.h[1], acc.y);
                acc.z = fmaf(m[t], (float)u.h[2], acc.z);
                acc.w = fmaf(m[t], (float)u.h[3], acc.w);
            }
        }
    }
    const float inv = inv_deg[node];
    acc.x *= inv; acc.y *= inv; acc.z *= inv; acc.w *= inv;
    unsigned short f[4] = {f2h(acc.x), f2h(acc.y), f2h(acc.z), f2h(acc.w)};
    *(int2*)(Agf16 + (size_t)node * 128 + q) = make_int2(
        (int)(f[0] | ((unsigned)f[1] << 16)), (int)(f[2] | ((unsigned)f[3] << 16)));
}

__global__ __launch_bounds__(256, 4) void gemm_kernel(
    const short* __restrict__ Agf16, const short* __restrict__ Xf16,
    const short* __restrict__ wfrag, const float* __restrict__ bias,
    float* __restrict__ Yf, short* __restrict__ Yf16,
    int n, int do_relu) {
    __shared__ __align__(16) short sT[2][64][64];
    const int tid = threadIdx.x;
    const int lane = tid & 63;
    const int wave = tid >> 6;
    const int ln15 = lane & 15;
    const int quad = lane >> 4;
    const int row0 = blockIdx.x * 64;
    const int wr0 = (wave & 1) * 32;
    const int wc0 = (wave >> 1) * 64;
    const int ctbase = (wave >> 1) * 4;

    f32x4 accM[2][4], accR[2][4];
#pragma unroll
    for (int i = 0; i < 2; ++i)
#pragma unroll
        for (int j = 0; j < 4; ++j) { accM[i][j] = (f32x4)(0.f); accR[i][j] = (f32x4)(0.f); }

    const short* pbase = (wave < 2) ? Agf16 : Xf16;
    const int rhalf = (wave & 1) * 32;
    const int rl = lane >> 3;
    const int gslot = (lane & 7) ^ rl;

    for (int kp = 0; kp < 2; ++kp) {
        __syncthreads();
#pragma unroll
        for (int i = 0; i < 4; ++i) {
            const int rloc = rhalf + i * 8;
            int grow = row0 + rloc + rl;
            if (grow >= n) grow = n - 1;
            const short* g = pbase + (size_t)grow * 128 + kp * 64 + gslot * 8;
            g2lds16(g, &sT[wave >> 1][rloc][0]);
        }
        __syncthreads();

#pragma unroll
        for (int ch = 0; ch < 2; ++ch) {
            const int chunk = kp * 2 + ch;
            h16x8 fAg[2], fX[2];
#pragma unroll
            for (int rt = 0; rt < 2; ++rt) {
                const int r = wr0 + rt * 16 + ln15;
                const int cc = (ch * 4 + quad) ^ (r & 7);
                fAg[rt] = *(const h16x8*)&sT[0][r][cc * 8];
                fX[rt]  = *(const h16x8*)&sT[1][r][cc * 8];
            }
#pragma unroll
            for (int ct = 0; ct < 4; ++ct) {
                const short* wb = wfrag + (chunk << 12) + ((ctbase + ct) << 9) + (lane << 3);
                const h16x8 wlh = *(const h16x8*)(wb);
                const h16x8 wll = *(const h16x8*)(wb + 16384);
                const h16x8 wrh = *(const h16x8*)(wb + 32768);
                const h16x8 wrl = *(const h16x8*)(wb + 49152);
#pragma unroll
                for (int rt = 0; rt < 2; ++rt) {
                    accM[rt][ct] = __builtin_amdgcn_mfma_f32_16x16x32_f16(fAg[rt], wlh, accM[rt][ct], 0, 0, 0);
                    accR[rt][ct] = __builtin_amdgcn_mfma_f32_16x16x32_f16(fAg[rt], wll, accR[rt][ct], 0, 0, 0);
                    accM[rt][ct] = __builtin_amdgcn_mfma_f32_16x16x32_f16(fX[rt],  wrh, accM[rt][ct], 0, 0, 0);
                    accR[rt][ct] = __builtin_amdgcn_mfma_f32_16x16x32_f16(fX[rt],  wrl, accR[rt][ct], 0, 0, 0);
                }
            }
        }
    }

#pragma unroll
    for (int rt = 0; rt < 2; ++rt) {
#pragma unroll
        for (int ct = 0; ct < 4; ++ct) {
            const int col = wc0 + ct * 16 + ln15;
            const float bv = bias[col];
#pragma unroll
            for (int r = 0; r < 4; ++r) {
                const int grow = row0 + wr0 + rt * 16 + quad * 4 + r;
                if (grow < n) {
                    float v = accM[rt][ct][r] + accR[rt][ct][r] * 4.8828125e-4f + bv;
                    if (do_relu) v = fmaxf(v, 0.f);
                    if (Yf) {
                        Yf[(size_t)grow * NDIM + col] = v;
                    } else {
                        Yf16[(size_t)grow * 128 + col] = (short)f2h(v);
                    }
                }
            }
        }
    }
}

// ---------------- host launcher ----------------
extern "C" void kernel_launch(void* const* d_in, const int* in_sizes, int n_in,
                              void* d_out, int out_size, void* d_ws, size_t ws_size,
                              hipStream_t stream) {
    const float* x0   = (const float*)d_in[0];
    const int*   eraw = (const int*)d_in[1];
    const float* Wl   = (const float*)d_in[2];
    const float* bl   = (const float*)d_in[3];
    const float* Wr   = (const float*)d_in[4];
    float* out = (float*)d_out;

    const int N = in_sizes[0] / NDIM;   // 50000
    const int E = in_sizes[1] / 2;      // 600000

    auto align_up = [](size_t v) { return (v + 255) & ~(size_t)255; };
    char* p = (char*)d_ws;
    int* idx = (int*)p;                 p += align_up((size_t)2 * E * 4);
    int* deg = (int*)p;                 p += align_up((size_t)(N + 1) * 4);
    int* flag = deg + N;
    int* row_start = (int*)p;           p += align_up((size_t)(N + 1) * 4);
    int* cursor = (int*)p;              p += align_up((size_t)N * 4);
    int* ssrc = (int*)p;                p += align_up((size_t)E * 4);
    float* invd = (float*)p;            p += align_up((size_t)N * 4);
    int* partials = (int*)p;            p += align_up((size_t)1024 * 4);
    short* wfrag = (short*)p;           p += align_up((size_t)327680 * 2);
    short* f16[3];
    for (int s = 0; s < 3; ++s) {
        f16[s] = (short*)p;             p += align_up((size_t)N * 128 * 2);
    }

    // ---- cooperative path: one dispatch for the whole pipeline ----
    static int g_grid = 0;
    static bool g_coop_ok = true;
    if (g_coop_ok && g_grid == 0) {
        int dev = 0;
        hipGetDevice(&dev);
        hipDeviceProp_t props;
        if (hipGetDeviceProperties(&props, dev) != hipSuccess || !props.cooperativeLaunch) {
            g_coop_ok = false;
        } else {
            int bpc = 0;
            if (hipOccupancyMaxActiveBlocksPerMultiprocessor(&bpc, mega_kernel, 256, 0) != hipSuccess
                || bpc <= 0) {
                g_coop_ok = false;
            } else {
                g_grid = bpc * props.multiProcessorCount;
                if (g_grid > 2048) g_grid = 2048;
            }
        }
        if (!g_coop_ok) (void)hipGetLastError();
    }

    bool done = false;
    if (g_coop_ok && g_grid > 0) {
        MegaArgs ha;
        ha.eraw = eraw; ha.Wl = Wl; ha.Wr = Wr; ha.bl = bl; ha.x0 = x0;
        ha.idx = idx; ha.deg = deg; ha.flag = flag;
        ha.row_start = row_start; ha.cursor = cursor; ha.partials = partials;
        ha.ssrc = ssrc; ha.invd = invd; ha.wfrag = wfrag;
        ha.f0 = f16[0]; ha.f1 = f16[1]; ha.f2 = f16[2];
        ha.out = out; ha.N = N; ha.E = E;
        void* kargs[] = {(void*)&ha};
        hipError_t err = hipLaunchCooperativeKernel(
            mega_kernel, dim3(g_grid), dim3(256), kargs, 0, stream);
        if (err == hipSuccess) {
            done = true;
        } else {
            (void)hipGetLastError();
            g_coop_ok = false;
        }
    }

    if (!done) {
        // fallback: proven R9 pipeline
        const int nb = (N + 1023) / 1024;
        hipMemsetAsync(deg, 0, (size_t)N * 4, stream);
        detect_kernel<<<1, 256, 0, stream>>>(eraw, flag, E);
        convert_kernel<<<(2 * E + 255) / 256, 256, 0, stream>>>(eraw, flag, idx, deg, E);
        deg_reduce_kernel<<<nb, 256, 0, stream>>>(deg, partials, N);
        scan_partials_kernel<<<1, 1024, 0, stream>>>(partials, nb, row_start, N);
        deg_downsweep_kernel<<<nb, 256, 0, stream>>>(deg, partials, row_start, cursor, invd, N);
        scatter_kernel<<<(E + 1023) / 1024, 256, 0, stream>>>(idx, cursor, ssrc, E);
        presplit_kernel<<<1280, 256, 0, stream>>>(Wl, Wr, wfrag, 327680);
        split_x_kernel<<<(N * 32 + 255) / 256, 256, 0, stream>>>(x0, f16[0], N * 32);
        int xs = 0;
        for (int l = 0; l < 5; ++l) {
            const int as_ = (xs + 1) % 3;
            const int ys = (xs + 2) % 3;
            aggregate_kernel<<<(N * 32 + 255) / 256, 256, 0, stream>>>(
                f16[xs], row_start, ssrc, invd, f16[as_], N);
            if (l < 4) {
                gemm_kernel<<<(N + 63) / 64, 256, 0, stream>>>(
                    f16[as_], f16[xs], wfrag + (size_t)l * 65536,
                    bl + (size_t)l * NDIM, nullptr, f16[ys], N, 1);
            } else {
                gemm_kernel<<<(N + 63) / 64, 256, 0, stream>>>(
                    f16[as_], f16[xs], wfrag + (size_t)l * 65536,
                    bl + (size_t)l * NDIM, out, nullptr, N, 0);
            }
            xs = ys;
        }
    }
}

// Round 11
// 358.550 us; speedup vs baseline: 6.3694x; 6.3694x over previous
//
#include <hip/hip_runtime.h>

#define NDIM 128

typedef __attribute__((ext_vector_type(8))) short s16x8;
typedef __attribute__((ext_vector_type(8))) _Float16 h16x8;
typedef __attribute__((ext_vector_type(4))) float f32x4;

// fp32 <-> fp16 (RNE via hardware cvt)
__device__ __forceinline__ unsigned short f2h(float f) {
    _Float16 h = (_Float16)f;
    return *(unsigned short*)&h;
}
__device__ __forceinline__ float h2f(unsigned short u) {
    _Float16 h = *(_Float16*)&u;
    return (float)h;
}

// async global->LDS, 16 B per lane; lds dest is wave-uniform base
// (lane l lands at base + l*16). Source is per-lane (pre-swizzle there).
__device__ __forceinline__ void g2lds16(const void* g, void* l) {
    __builtin_amdgcn_global_load_lds(
        (const __attribute__((address_space(1))) void*)g,
        (__attribute__((address_space(3))) void*)l, 16, 0, 0);
}

// ---- R11 merge 1: zero deg + detect layout in ONE kernel ----
// Grid-stride zero of deg[0..N-1]; block 0 exclusively owns the flag word
// (zeroes it, detects, writes it) — no cross-block race on flag.
__global__ __launch_bounds__(256) void init_detect_kernel(
    const int* __restrict__ raw, int* __restrict__ deg, int* __restrict__ flag,
    int E, int N) {
    const int tid = threadIdx.x;
    const int gtid = blockIdx.x * 256 + tid;
    const int gsz = gridDim.x * 256;
    for (int i = gtid; i < N; i += gsz) deg[i] = 0;
    if (blockIdx.x == 0) {
        __shared__ int any_nz;
        if (tid == 0) any_nz = 0;
        __syncthreads();
        int local = 0;
        const int samples = (E < 4096) ? E : 4096;
#pragma unroll
        for (int j = 0; j < 16; ++j) {
            int i = tid * 16 + j;
            if (i < samples) local |= raw[2 * i + 1];
        }
        if (local) atomicOr(&any_nz, 1);
        __syncthreads();
        if (tid == 0) *flag = any_nz;   // nonzero -> int32 layout
    }
}

// convert + fused degree histogram
__global__ void convert_kernel(const int* __restrict__ raw, const int* __restrict__ flag,
                               int* __restrict__ idx, int* __restrict__ deg, int E) {
    int i = blockIdx.x * 256 + threadIdx.x;
    if (i >= 2 * E) return;
    int v = (*flag == 0) ? raw[2 * i] : raw[i];
    idx[i] = v;
    if (i >= E) atomicAdd(&deg[v], 1);   // dst words
}

__global__ __launch_bounds__(256) void deg_reduce_kernel(
    const int* __restrict__ deg, int* __restrict__ partials, int n) {
    const int base = blockIdx.x * 1024;
    const int tid = threadIdx.x;
    int s = 0;
#pragma unroll
    for (int j = 0; j < 4; ++j) {
        int i = base + tid * 4 + j;
        if (i < n) s += deg[i];
    }
#pragma unroll
    for (int off = 32; off; off >>= 1) s += __shfl_down(s, off);
    __shared__ int ws[4];
    if ((tid & 63) == 0) ws[tid >> 6] = s;
    __syncthreads();
    if (tid == 0) partials[blockIdx.x] = ws[0] + ws[1] + ws[2] + ws[3];
}

__global__ void scan_partials_kernel(int* __restrict__ partials, int nb,
                                     int* __restrict__ row_start, int n) {
    __shared__ int sh[1024];
    const int tid = threadIdx.x;
    int v = (tid < nb) ? partials[tid] : 0;
    sh[tid] = v;
    __syncthreads();
    for (int off = 1; off < 1024; off <<= 1) {
        int a = sh[tid];
        int b = (tid >= off) ? sh[tid - off] : 0;
        __syncthreads();
        sh[tid] = a + b;
        __syncthreads();
    }
    if (tid < nb) partials[tid] = (tid == 0) ? 0 : sh[tid - 1];
    if (tid == 0) row_start[n] = sh[1023];
}

__global__ __launch_bounds__(256) void deg_downsweep_kernel(
    const int* __restrict__ deg, const int* __restrict__ partials,
    int* __restrict__ row_start, int* __restrict__ cursor,
    float* __restrict__ inv_deg, int n) {
    const int base = blockIdx.x * 1024;
    const int tid = threadIdx.x;
    const int i0 = base + tid * 4;
    int d[4];
    int s = 0;
#pragma unroll
    for (int j = 0; j < 4; ++j) {
        int i = i0 + j;
        d[j] = (i < n) ? deg[i] : 0;
        s += d[j];
    }
    const int lane = tid & 63;
    int incl = s;
#pragma unroll
    for (int off = 1; off < 64; off <<= 1) {
        int t = __shfl_up(incl, off);
        if (lane >= off) incl += t;
    }
    __shared__ int wsum[4];
    if (lane == 63) wsum[tid >> 6] = incl;
    __syncthreads();
    int woff = 0;
    const int w = tid >> 6;
    for (int k = 0; k < w; ++k) woff += wsum[k];
    int excl = incl - s + woff + partials[blockIdx.x];
#pragma unroll
    for (int j = 0; j < 4; ++j) {
        int i = i0 + j;
        if (i < n) {
            row_start[i] = excl;
            cursor[i] = excl;
            inv_deg[i] = 1.0f / (float)max(d[j], 1);
            excl += d[j];
        }
    }
}

// scatter v3: 8 edges/thread (atomic->store is 2 dependent round-trips;
// 8 independent chains in flight)
__global__ __launch_bounds__(256) void scatter_kernel(
    const int* __restrict__ idx, int* __restrict__ cursor,
    int* __restrict__ sorted_src, int E) {
    const int i0 = (blockIdx.x * 256 + threadIdx.x) * 8;
    if (i0 >= E) return;
    int s[8], d[8], p[8];
#pragma unroll
    for (int j = 0; j < 8; ++j) {
        if (i0 + j < E) {
            s[j] = idx[i0 + j];
            d[j] = idx[E + i0 + j];
        }
    }
#pragma unroll
    for (int j = 0; j < 8; ++j)
        if (i0 + j < E) p[j] = atomicAdd(&cursor[d[j]], 1);
#pragma unroll
    for (int j = 0; j < 8; ++j)
        if (i0 + j < E) sorted_src[p[j]] = s[j];
}

// ---- R11 merge 2: presplit W + split x0 in ONE kernel (index-split) ----
// presplit v3 (items 0..327679): W -> B-frag order, fp16 hi + lo*2^11.
// wfrag[l][plane(4)][chunk(4)][ct(8)][lane(64)][j(8)], plane: 0=Wl-hi,
// 1=Wl-lo*2^11, 2=Wr-hi, 3=Wr-lo*2^11. Element (lane,j) of (ct,chunk):
// n = ct*16 + (lane&15), k = chunk*32 + (lane>>4)*8 + j  [B-frag, m89/m91].
// split_x (items 327680..): x0 -> fp16 plane [node][128], 4 floats/item.
__global__ __launch_bounds__(256) void prep_kernel(
    const float* __restrict__ Wl, const float* __restrict__ Wr,
    short* __restrict__ wfrag,
    const float* __restrict__ X, short* __restrict__ Xf16, int total4) {
    int t = blockIdx.x * 256 + threadIdx.x;
    if (t < 327680) {
        int j = t & 7;
        int lane = (t >> 3) & 63;
        int ct = (t >> 9) & 7;
        int chunk = (t >> 12) & 3;
        int plane = (t >> 14) & 3;
        int l = t >> 16;
        int nn = ct * 16 + (lane & 15);
        int k = chunk * 32 + (lane >> 4) * 8 + j;
        const float* src = (plane < 2) ? Wl : Wr;
        float v = src[(size_t)l * 16384 + (size_t)k * 128 + nn];
        unsigned short h = f2h(v);
        wfrag[t] = (plane & 1) ? (short)f2h((v - h2f(h)) * 2048.0f) : (short)h;
    } else {
        int i = t - 327680;
        if (i >= total4) return;
        float4 v = *(const float4*)(X + (size_t)i * 4);
        unsigned short f[4] = {f2h(v.x), f2h(v.y), f2h(v.z), f2h(v.w)};
        *(int2*)(Xf16 + (size_t)i * 4) = make_int2(
            (int)(f[0] | ((unsigned)f[1] << 16)), (int)(f[2] | ((unsigned)f[3] << 16)));
    }
}

// ---------------- mean aggregation v7 (fp16 in AND out; R9 proven) -------
__global__ __launch_bounds__(256) void aggregate_kernel(
    const short* __restrict__ Xf16, const int* __restrict__ row_start,
    const int* __restrict__ sorted_src, const float* __restrict__ inv_deg,
    short* __restrict__ Agf16, int n) {
    int gid = blockIdx.x * 256 + threadIdx.x;
    int node = gid >> 5;
    if (node >= n) return;
    const int lane32 = threadIdx.x & 31;
    const int q = lane32 << 2;          // 4 elements per lane
    const int beg = row_start[node];
    const int end = row_start[node + 1];
    float4 acc = make_float4(0.f, 0.f, 0.f, 0.f);
    for (int base = beg; base < end; base += 32) {
        const int cnt = min(end - base, 32);
        const int my_src = (lane32 < cnt) ? sorted_src[base + lane32] : 0;
        for (int jb = 0; jb < cnt; jb += 8) {
            int2 v[8];
            float m[8];
#pragma unroll
            for (int t = 0; t < 8; ++t) {
                const int j = jb + t;
                const int js = (j < cnt) ? j : (cnt - 1);
                const int s = __shfl(my_src, js, 32);
                v[t] = *(const int2*)(Xf16 + (size_t)s * 128 + q);
                m[t] = (j < cnt) ? 1.f : 0.f;
            }
#pragma unroll
            for (int t = 0; t < 8; ++t) {
                union { int2 i2; _Float16 h[4]; } u;
                u.i2 = v[t];
                acc.x = fmaf(m[t], (float)u.h[0], acc.x);
                acc.y = fmaf(m[t], (float)u.h[1], acc.y);
                acc.z = fmaf(m[t], (float)u.h[2], acc.z);
                acc.w = fmaf(m[t], (float)u.h[3], acc.w);
            }
        }
    }
    const float inv = inv_deg[node];
    acc.x *= inv; acc.y *= inv; acc.z *= inv; acc.w *= inv;
    unsigned short f[4] = {f2h(acc.x), f2h(acc.y), f2h(acc.z), f2h(acc.w)};
    *(int2*)(Agf16 + (size_t)node * 128 + q) = make_int2(
        (int)(f[0] | ((unsigned)f[1] << 16)), (int)(f[2] | ((unsigned)f[3] << 16)));
}

// ------- GEMM v14 (fp16 activations, f16 MFMA, split-fp16 W; R9 proven) ----
// Per kp-half: g2lds staging (linear LDS dest + pre-swizzled global source,
// involution slot c^rl, rule #21), barrier, 2-chunk MFMA loop. Dual
// accumulators: accM = A*W-hi, accR = A*(W-lo*2^11); epilogue
// v = accM + accR/2048 + bias. 128 MFMAs/block, LDS 16 KB.
__global__ __launch_bounds__(256, 4) void gemm_kernel(
    const short* __restrict__ Agf16, const short* __restrict__ Xf16,
    const short* __restrict__ wfrag,   // this layer's 65536-elem block
    const float* __restrict__ bias,
    float* __restrict__ Yf, short* __restrict__ Yf16,
    int n, int do_relu) {
    __shared__ __align__(16) short sT[2][64][64];   // 16 KB: Ag, X fp16 half-rows
    const int tid = threadIdx.x;
    const int lane = tid & 63;
    const int wave = tid >> 6;
    const int ln15 = lane & 15;
    const int quad = lane >> 4;
    const int row0 = blockIdx.x * 64;
    const int wr0 = (wave & 1) * 32;     // wave's row offset
    const int wc0 = (wave >> 1) * 64;    // wave's col offset
    const int ctbase = (wave >> 1) * 4;  // global col-tile base

    f32x4 accM[2][4], accR[2][4];
#pragma unroll
    for (int i = 0; i < 2; ++i)
#pragma unroll
        for (int j = 0; j < 4; ++j) { accM[i][j] = (f32x4)(0.f); accR[i][j] = (f32x4)(0.f); }

    // staging geometry: plane p = wave>>1 (0=Ag, 1=X); wave&1 selects row
    // half. Per issue: 8 rows x 128 B = 1 KB; lane l -> row rbase+(l>>3),
    // slot c=l&7; source slot = c ^ (rl&7)  [involution].
    const short* pbase = (wave < 2) ? Agf16 : Xf16;
    const int rhalf = (wave & 1) * 32;
    const int rl = lane >> 3;                // row within 8-row group
    const int gslot = (lane & 7) ^ rl;       // pre-swizzled source slot

    for (int kp = 0; kp < 2; ++kp) {
        __syncthreads();   // prior half's ds_reads complete before overwrite
#pragma unroll
        for (int i = 0; i < 4; ++i) {
            const int rloc = rhalf + i * 8;
            int grow = row0 + rloc + rl;
            if (grow >= n) grow = n - 1;
            const short* g = pbase + (size_t)grow * 128 + kp * 64 + gslot * 8;
            g2lds16(g, &sT[wave >> 1][rloc][0]);
        }
        __syncthreads();   // drains vmcnt(0): staging visible to all waves

#pragma unroll
        for (int ch = 0; ch < 2; ++ch) {
            const int chunk = kp * 2 + ch;
            h16x8 fAg[2], fX[2];
#pragma unroll
            for (int rt = 0; rt < 2; ++rt) {
                const int r = wr0 + rt * 16 + ln15;
                const int cc = (ch * 4 + quad) ^ (r & 7);
                fAg[rt] = *(const h16x8*)&sT[0][r][cc * 8];
                fX[rt]  = *(const h16x8*)&sT[1][r][cc * 8];
            }
#pragma unroll
            for (int ct = 0; ct < 4; ++ct) {
                const short* wb = wfrag + (chunk << 12) + ((ctbase + ct) << 9) + (lane << 3);
                const h16x8 wlh = *(const h16x8*)(wb);            // Wl-hi
                const h16x8 wll = *(const h16x8*)(wb + 16384);    // Wl-lo*2^11
                const h16x8 wrh = *(const h16x8*)(wb + 32768);    // Wr-hi
                const h16x8 wrl = *(const h16x8*)(wb + 49152);    // Wr-lo*2^11
#pragma unroll
                for (int rt = 0; rt < 2; ++rt) {
                    accM[rt][ct] = __builtin_amdgcn_mfma_f32_16x16x32_f16(fAg[rt], wlh, accM[rt][ct], 0, 0, 0);
                    accR[rt][ct] = __builtin_amdgcn_mfma_f32_16x16x32_f16(fAg[rt], wll, accR[rt][ct], 0, 0, 0);
                    accM[rt][ct] = __builtin_amdgcn_mfma_f32_16x16x32_f16(fX[rt],  wrh, accM[rt][ct], 0, 0, 0);
                    accR[rt][ct] = __builtin_amdgcn_mfma_f32_16x16x32_f16(fX[rt],  wrl, accR[rt][ct], 0, 0, 0);
                }
            }
        }
    }

    // epilogue: C/D layout col=lane&15, row=quad*4+reg [m89]
#pragma unroll
    for (int rt = 0; rt < 2; ++rt) {
#pragma unroll
        for (int ct = 0; ct < 4; ++ct) {
            const int col = wc0 + ct * 16 + ln15;
            const float bv = bias[col];
#pragma unroll
            for (int r = 0; r < 4; ++r) {
                const int grow = row0 + wr0 + rt * 16 + quad * 4 + r;
                if (grow < n) {
                    float v = accM[rt][ct][r] + accR[rt][ct][r] * 4.8828125e-4f + bv;
                    if (do_relu) v = fmaxf(v, 0.f);
                    if (Yf) {
                        Yf[(size_t)grow * NDIM + col] = v;
                    } else {
                        Yf16[(size_t)grow * 128 + col] = (short)f2h(v);
                    }
                }
            }
        }
    }
}

// ---------------- host launcher ----------------
extern "C" void kernel_launch(void* const* d_in, const int* in_sizes, int n_in,
                              void* d_out, int out_size, void* d_ws, size_t ws_size,
                              hipStream_t stream) {
    const float* x0   = (const float*)d_in[0];
    const int*   eraw = (const int*)d_in[1];
    const float* Wl   = (const float*)d_in[2];
    const float* bl   = (const float*)d_in[3];
    const float* Wr   = (const float*)d_in[4];
    float* out = (float*)d_out;

    const int N = in_sizes[0] / NDIM;   // 50000
    const int E = in_sizes[1] / 2;      // 600000

    auto align_up = [](size_t v) { return (v + 255) & ~(size_t)255; };
    char* p = (char*)d_ws;
    int* idx = (int*)p;                 p += align_up((size_t)2 * E * 4);
    int* deg = (int*)p;                 p += align_up((size_t)(N + 1) * 4);
    int* flag = deg + N;
    int* row_start = (int*)p;           p += align_up((size_t)(N + 1) * 4);
    int* cursor = (int*)p;              p += align_up((size_t)N * 4);
    int* ssrc = (int*)p;                p += align_up((size_t)E * 4);
    float* invd = (float*)p;            p += align_up((size_t)N * 4);
    int* partials = (int*)p;            p += align_up((size_t)1024 * 4);
    short* wfrag = (short*)p;           p += align_up((size_t)327680 * 2);
    // 3 rotating fp16 activation planes [node][128]
    short* f16[3];
    for (int s = 0; s < 3; ++s) {
        f16[s] = (short*)p;             p += align_up((size_t)N * 128 * 2);
    }

    const int nb = (N + 1023) / 1024;
    const int preptotal = 327680 + N * 32;

    init_detect_kernel<<<256, 256, 0, stream>>>(eraw, deg, flag, E, N);
    convert_kernel<<<(2 * E + 255) / 256, 256, 0, stream>>>(eraw, flag, idx, deg, E);
    deg_reduce_kernel<<<nb, 256, 0, stream>>>(deg, partials, N);
    scan_partials_kernel<<<1, 1024, 0, stream>>>(partials, nb, row_start, N);
    deg_downsweep_kernel<<<nb, 256, 0, stream>>>(deg, partials, row_start, cursor, invd, N);
    scatter_kernel<<<(E + 2047) / 2048, 256, 0, stream>>>(idx, cursor, ssrc, E);
    prep_kernel<<<(preptotal + 255) / 256, 256, 0, stream>>>(
        Wl, Wr, wfrag, x0, f16[0], N * 32);

    // slot rotation per layer: X=xs, AG=(xs+1)%3, Y=(xs+2)%3 (all distinct)
    int xs = 0;
    for (int l = 0; l < 5; ++l) {
        const int as_ = (xs + 1) % 3;
        const int ys = (xs + 2) % 3;
        aggregate_kernel<<<(N * 32 + 255) / 256, 256, 0, stream>>>(
            f16[xs], row_start, ssrc, invd, f16[as_], N);
        if (l < 4) {
            gemm_kernel<<<(N + 63) / 64, 256, 0, stream>>>(
                f16[as_], f16[xs], wfrag + (size_t)l * 65536,
                bl + (size_t)l * NDIM, nullptr, f16[ys], N, 1);
        } else {
            gemm_kernel<<<(N + 63) / 64, 256, 0, stream>>>(
                f16[as_], f16[xs], wfrag + (size_t)l * 65536,
                bl + (size_t)l * NDIM, out, nullptr, N, 0);
        }
        xs = ys;
    }
}